// Round 4
// baseline (113.432 us; speedup 1.0000x reference)
//
#include <hip/hip_runtime.h>

#define TSD 512      // TS (feature dim)
#define SRC 256
#define TGT 256
#define NB  4        // batch

// ---------------------------------------------------------------------------
// Projection GEMM: 64x64 tiles, 16x16 threads, 4x4 micro-tile, BK=16.
// z=0: hp[r][o]     = (hid . Wh)[r][o]                (row-major [r][o])
// z=1: epT[b][o][s] = (enc . We)[r][o] + bias[o]      (TRANSPOSED [o][s])
// ---------------------------------------------------------------------------
__global__ __launch_bounds__(256) void proj_kernel(
    const float* __restrict__ hid, const float* __restrict__ enc,
    const float* __restrict__ W, const float* __restrict__ bias,
    float* __restrict__ hp, float* __restrict__ epT)
{
    const int z = blockIdx.z;
    const float* __restrict__ X = z ? enc : hid;
    const int wofs = z ? TSD : 0;

    __shared__ float Xs[16][68];   // [k][m]
    __shared__ float Ws[16][68];   // [k][n]

    const int tx = threadIdx.x, ty = threadIdx.y;
    const int tid = ty * 16 + tx;
    const int o0 = blockIdx.x * 64;
    const int r0 = blockIdx.y * 64;

    const int m  = tid >> 2;        // 0..63
    const int kq = (tid & 3) * 4;   // 0,4,8,12

    float acc[4][4] = {};

    for (int k0 = 0; k0 < TSD; k0 += 16) {
        __syncthreads();
        float4 av = *reinterpret_cast<const float4*>(&X[(r0 + m) * TSD + k0 + kq]);
        float4 wv = *reinterpret_cast<const float4*>(&W[(o0 + m) * (2 * TSD) + wofs + k0 + kq]);
        Xs[kq + 0][m] = av.x; Xs[kq + 1][m] = av.y; Xs[kq + 2][m] = av.z; Xs[kq + 3][m] = av.w;
        Ws[kq + 0][m] = wv.x; Ws[kq + 1][m] = wv.y; Ws[kq + 2][m] = wv.z; Ws[kq + 3][m] = wv.w;
        __syncthreads();
        #pragma unroll
        for (int k = 0; k < 16; ++k) {
            float4 a  = *reinterpret_cast<const float4*>(&Xs[k][ty * 4]);
            float4 bb = *reinterpret_cast<const float4*>(&Ws[k][tx * 4]);
            float ar[4] = {a.x, a.y, a.z, a.w};
            float br[4] = {bb.x, bb.y, bb.z, bb.w};
            #pragma unroll
            for (int i = 0; i < 4; ++i)
                #pragma unroll
                for (int j = 0; j < 4; ++j)
                    acc[i][j] = fmaf(ar[i], br[j], acc[i][j]);
        }
    }

    if (z) {
        const int bb_ = r0 >> 8;              // batch of this row-tile
        const int sl  = (r0 & 255) + ty * 4;  // s within batch
        #pragma unroll
        for (int j = 0; j < 4; ++j) {
            const int o = o0 + tx * 4 + j;
            const float bj = bias[o];
            float4 val;
            val.x = acc[0][j] + bj;
            val.y = acc[1][j] + bj;
            val.z = acc[2][j] + bj;
            val.w = acc[3][j] + bj;
            *reinterpret_cast<float4*>(&epT[((size_t)bb_ * TSD + o) * SRC + sl]) = val;
        }
    } else {
        #pragma unroll
        for (int i = 0; i < 4; ++i) {
            const int r = r0 + ty * 4 + i;
            float4 o4;
            o4.x = acc[i][0]; o4.y = acc[i][1];
            o4.z = acc[i][2]; o4.w = acc[i][3];
            *reinterpret_cast<float4*>(&hp[r * TSD + o0 + tx * 4]) = o4;
        }
    }
}

// ---------------------------------------------------------------------------
// Eigen-style rational tanh (deg 13/6 minimax on [-7.905, 7.905], err ~1e-6).
// Returns acc + vv * tanh(u). 15 full-rate VALU + 1 rcp (trans).
// ---------------------------------------------------------------------------
__device__ __forceinline__ float tanh_term(float u, float vv, float acc) {
    const float CL = 7.90531110763549805f;
    u = fminf(fmaxf(u, -CL), CL);
    const float y = u * u;
    float P = fmaf(y, -2.76076847742355e-16f, 2.00018790482477e-13f);
    P = fmaf(y, P, -8.60467152213735e-11f);
    P = fmaf(y, P, 5.12229709037114e-08f);
    P = fmaf(y, P, 1.48572235717979e-05f);
    P = fmaf(y, P, 6.37261928875436e-04f);
    P = fmaf(y, P, 4.89352455891786e-03f);
    float Q = fmaf(y, 1.19825839466702e-06f, 1.18534705686654e-04f);
    Q = fmaf(y, Q, 2.26843463243900e-03f);
    Q = fmaf(y, Q, 4.89352518554385e-03f);
    const float w = vv * u;
    return fmaf(w * P, __builtin_amdgcn_rcpf(Q), acc);
}

__device__ __forceinline__ float wave_red_sum(float v) {
    #pragma unroll
    for (int off = 1; off < 64; off <<= 1) v += __shfl_xor(v, off, 64);
    return v;
}
__device__ __forceinline__ float wave_red_max(float v) {
    #pragma unroll
    for (int off = 1; off < 64; off <<= 1) v = fmaxf(v, __shfl_xor(v, off, 64));
    return v;
}
// 256-thread-group reductions inside a 512-thread block (all threads must call)
__device__ __forceinline__ float grp_sum(float val, float (*red)[4], int g, int tid) {
    float w = wave_red_sum(val);
    __syncthreads();
    if ((tid & 63) == 0) red[g][(tid >> 6) & 3] = w;
    __syncthreads();
    return red[g][0] + red[g][1] + red[g][2] + red[g][3];
}
__device__ __forceinline__ float grp_max(float val, float (*red)[4], int g, int tid) {
    float w = wave_red_max(val);
    __syncthreads();
    if ((tid & 63) == 0) red[g][(tid >> 6) & 3] = w;
    __syncthreads();
    return fmaxf(fmaxf(red[g][0], red[g][1]), fmaxf(red[g][2], red[g][3]));
}

// ---------------------------------------------------------------------------
// Fused score + softmax + context.
// Block = 512 threads = (oh in 0..1) x (s in 0..255); TB=2 target rows/block.
// Each thread loads e once, accumulates BOTH t rows (load sharing).
// score[t][s] = sum_o v[o] * tanh(hp[t][o] + epT[o][s])
// ---------------------------------------------------------------------------
__global__ __launch_bounds__(512) void attn_kernel(
    const float* __restrict__ hp, const float* __restrict__ epT,
    const float* __restrict__ enc, const int* __restrict__ mask,
    const float* __restrict__ v,
    float* __restrict__ ctx_out, float* __restrict__ probs_out)
{
    __shared__ float accs[2][2][SRC];   // [t][oh][s]
    __shared__ float p_lds[2][SRC];
    __shared__ float red2[2][4];

    const int tid = threadIdx.x;
    const int oh = __builtin_amdgcn_readfirstlane(tid >> 8);  // wave-uniform
    const int s  = tid & 255;
    const int b  = blockIdx.y;
    const int t0 = blockIdx.x * 2;

    const float* __restrict__ hp0 = hp + ((size_t)(b * TGT + t0)) * TSD + oh * 256;  // SGPR base
    const float* __restrict__ hp1 = hp0 + TSD;
    const float* __restrict__ vo  = v + oh * 256;
    const float* __restrict__ epb = epT + (size_t)b * TSD * SRC + (size_t)oh * 256 * SRC;

    float acc0 = 0.f, acc1 = 0.f;
    #pragma unroll 4
    for (int oi = 0; oi < 256; ++oi) {
        const float e  = epb[oi * SRC + s];   // coalesced, L2-hot
        const float vv = vo[oi];              // s_load
        acc0 = tanh_term(hp0[oi] + e, vv, acc0);
        acc1 = tanh_term(hp1[oi] + e, vv, acc1);
    }
    accs[0][oh][s] = acc0;
    accs[1][oh][s] = acc1;
    __syncthreads();

    // softmax: group oh handles target row t = t0 + oh
    const float score = accs[oh][0][s] + accs[oh][1][s];
    const float bmax = grp_max(score, red2, oh, tid);
    const float eE = __expf(score - bmax);
    const float sE = grp_sum(eE, red2, oh, tid);
    const float q = eE / sE;
    const float mq = q * (float)mask[b * SRC + s];
    const float smq = grp_sum(mq, red2, oh, tid);
    const float p = mq / (smq + 1e-12f);
    p_lds[oh][s] = p;
    probs_out[((size_t)(b * TGT + t0 + oh)) * SRC + s] = p;
    __syncthreads();

    // context: thread owns output column d = tid (512 cols), both t rows
    float c0 = 0.f, c1 = 0.f;
    const float* __restrict__ encb = enc + (size_t)b * SRC * TSD;
    #pragma unroll 4
    for (int s2 = 0; s2 < SRC; ++s2) {
        const float ev = encb[s2 * TSD + tid];
        c0 = fmaf(p_lds[0][s2], ev, c0);
        c1 = fmaf(p_lds[1][s2], ev, c1);
    }
    ctx_out[((size_t)(b * TGT + t0 + 0)) * TSD + tid] = c0;
    ctx_out[((size_t)(b * TGT + t0 + 1)) * TSD + tid] = c1;
}

extern "C" void kernel_launch(void* const* d_in, const int* in_sizes, int n_in,
                              void* d_out, int out_size, void* d_ws, size_t ws_size,
                              hipStream_t stream) {
    const float* hid  = (const float*)d_in[0];   // (4,256,512)
    const float* enc  = (const float*)d_in[1];   // (4,256,512)
    const int*   mask = (const int*)  d_in[2];   // (4,256)
    const float* W    = (const float*)d_in[3];   // (512,1024)
    const float* bias = (const float*)d_in[4];   // (512,)
    const float* v    = (const float*)d_in[5];   // (512,)

    float* out   = (float*)d_out;
    float* ctx   = out;                       // 4*256*512
    float* probs = out + NB * TGT * TSD;      // 4*256*256

    float* hp  = (float*)d_ws;                // 1024*512
    float* epT = hp + NB * TGT * TSD;         // 4*512*256 (+bias, transposed)

    dim3 pb(16, 16);
    dim3 pg(TSD / 64, (NB * TGT) / 64, 2);
    proj_kernel<<<pg, pb, 0, stream>>>(hid, enc, W, bias, hp, epT);

    dim3 ag(TGT / 2, NB);
    attn_kernel<<<ag, 512, 0, stream>>>(hp, epT, enc, mask, v, ctx, probs);
}

// Round 5
// 93.450 us; speedup vs baseline: 1.2138x; 1.2138x over previous
//
#include <hip/hip_runtime.h>

#define TSD 512      // TS (feature dim)
#define SRC 256
#define TGT 256
#define NB  4        // batch
#define KSCALE 2.885390081777927f   // 2*log2(e): exp2(K*x) == exp(2x)

// ---------------------------------------------------------------------------
// Projection GEMM: 64x64 tiles, 16x16 threads, 4x4 micro-tile, BK=16.
// z=0: hp'[r][o]    = K * (hid . Wh)[r][o]                 (row-major [r][o])
// z=1: epT[b][o][s] = K * ((enc . We)[r][o] + bias[o])     (TRANSPOSED [o][s])
// ---------------------------------------------------------------------------
__global__ __launch_bounds__(256) void proj_kernel(
    const float* __restrict__ hid, const float* __restrict__ enc,
    const float* __restrict__ W, const float* __restrict__ bias,
    float* __restrict__ hp, float* __restrict__ epT)
{
    const int z = blockIdx.z;
    const float* __restrict__ X = z ? enc : hid;
    const int wofs = z ? TSD : 0;

    __shared__ float Xs[16][68];   // [k][m]
    __shared__ float Ws[16][68];   // [k][n]

    const int tx = threadIdx.x, ty = threadIdx.y;
    const int tid = ty * 16 + tx;
    const int o0 = blockIdx.x * 64;
    const int r0 = blockIdx.y * 64;

    const int m  = tid >> 2;        // 0..63
    const int kq = (tid & 3) * 4;   // 0,4,8,12

    float acc[4][4] = {};

    for (int k0 = 0; k0 < TSD; k0 += 16) {
        __syncthreads();
        float4 av = *reinterpret_cast<const float4*>(&X[(r0 + m) * TSD + k0 + kq]);
        float4 wv = *reinterpret_cast<const float4*>(&W[(o0 + m) * (2 * TSD) + wofs + k0 + kq]);
        Xs[kq + 0][m] = av.x; Xs[kq + 1][m] = av.y; Xs[kq + 2][m] = av.z; Xs[kq + 3][m] = av.w;
        Ws[kq + 0][m] = wv.x; Ws[kq + 1][m] = wv.y; Ws[kq + 2][m] = wv.z; Ws[kq + 3][m] = wv.w;
        __syncthreads();
        #pragma unroll
        for (int k = 0; k < 16; ++k) {
            float4 a  = *reinterpret_cast<const float4*>(&Xs[k][ty * 4]);
            float4 bb = *reinterpret_cast<const float4*>(&Ws[k][tx * 4]);
            float ar[4] = {a.x, a.y, a.z, a.w};
            float br[4] = {bb.x, bb.y, bb.z, bb.w};
            #pragma unroll
            for (int i = 0; i < 4; ++i)
                #pragma unroll
                for (int j = 0; j < 4; ++j)
                    acc[i][j] = fmaf(ar[i], br[j], acc[i][j]);
        }
    }

    if (z) {
        const int bb_ = r0 >> 8;              // batch of this row-tile
        const int sl  = (r0 & 255) + ty * 4;  // s within batch
        #pragma unroll
        for (int j = 0; j < 4; ++j) {
            const int o = o0 + tx * 4 + j;
            const float bj = bias[o];
            float4 val;
            val.x = (acc[0][j] + bj) * KSCALE;
            val.y = (acc[1][j] + bj) * KSCALE;
            val.z = (acc[2][j] + bj) * KSCALE;
            val.w = (acc[3][j] + bj) * KSCALE;
            *reinterpret_cast<float4*>(&epT[((size_t)bb_ * TSD + o) * SRC + sl]) = val;
        }
    } else {
        #pragma unroll
        for (int i = 0; i < 4; ++i) {
            const int r = r0 + ty * 4 + i;
            float4 o4;
            o4.x = acc[i][0] * KSCALE; o4.y = acc[i][1] * KSCALE;
            o4.z = acc[i][2] * KSCALE; o4.w = acc[i][3] * KSCALE;
            *reinterpret_cast<float4*>(&hp[r * TSD + o0 + tx * 4]) = o4;
        }
    }
}

// ---------------------------------------------------------------------------
// Reductions (256-thread block = 4 waves); dual variants share the syncs.
// ---------------------------------------------------------------------------
__device__ __forceinline__ float wave_red_sum(float v) {
    #pragma unroll
    for (int off = 1; off < 64; off <<= 1) v += __shfl_xor(v, off, 64);
    return v;
}
__device__ __forceinline__ float wave_red_max(float v) {
    #pragma unroll
    for (int off = 1; off < 64; off <<= 1) v = fmaxf(v, __shfl_xor(v, off, 64));
    return v;
}
__device__ __forceinline__ float block_sum(float val, float (*red)[4], int tid) {
    float w = wave_red_sum(val);
    __syncthreads();
    if ((tid & 63) == 0) red[0][tid >> 6] = w;
    __syncthreads();
    return red[0][0] + red[0][1] + red[0][2] + red[0][3];
}
__device__ __forceinline__ float2 block_sum2(float x, float y, float (*red)[4], int tid) {
    float wx = wave_red_sum(x), wy = wave_red_sum(y);
    __syncthreads();
    if ((tid & 63) == 0) { red[0][tid >> 6] = wx; red[1][tid >> 6] = wy; }
    __syncthreads();
    float2 r;
    r.x = red[0][0] + red[0][1] + red[0][2] + red[0][3];
    r.y = red[1][0] + red[1][1] + red[1][2] + red[1][3];
    return r;
}
__device__ __forceinline__ float2 block_max2(float x, float y, float (*red)[4], int tid) {
    float wx = wave_red_max(x), wy = wave_red_max(y);
    __syncthreads();
    if ((tid & 63) == 0) { red[0][tid >> 6] = wx; red[1][tid >> 6] = wy; }
    __syncthreads();
    float2 r;
    r.x = fmaxf(fmaxf(red[0][0], red[0][1]), fmaxf(red[0][2], red[0][3]));
    r.y = fmaxf(fmaxf(red[1][0], red[1][1]), fmaxf(red[1][2], red[1][3]));
    return r;
}

// ---------------------------------------------------------------------------
// Fused score + softmax + context.
// Block = 256 threads = 4 waves: wave w -> (t = w&1, o-half = w>>1).
// Lane owns 4 consecutive s (float4 epT loads). 2 target rows per block.
// score[t][s] = sumv - 2 * sum_o v[o] / (exp2(hp'[t][o] + epT[o][s]) + 1)
// ---------------------------------------------------------------------------
__global__ __launch_bounds__(256) void attn_kernel(
    const float* __restrict__ hp, const float* __restrict__ epT,
    const float* __restrict__ enc, const int* __restrict__ mask,
    const float* __restrict__ v,
    float* __restrict__ ctx_out, float* __restrict__ probs_out)
{
    __shared__ float accs[2][2][SRC];   // [t][oh][s]
    __shared__ float p_lds[2][SRC];
    __shared__ float red[2][4];

    const int tid  = threadIdx.x;
    const int lane = tid & 63;
    const int tl   = __builtin_amdgcn_readfirstlane((tid >> 6) & 1);  // wave-uniform t
    const int oh   = __builtin_amdgcn_readfirstlane(tid >> 7);        // wave-uniform o-half
    const int b  = blockIdx.y;
    const int t0 = blockIdx.x * 2;

    const float* __restrict__ hpt = hp + ((size_t)(b * TGT + t0 + tl)) * TSD + oh * 256; // SGPR
    const float* __restrict__ vo  = v + oh * 256;                                        // SGPR
    const float* __restrict__ epb = epT + (size_t)b * TSD * SRC + (size_t)oh * 256 * SRC + 4 * lane;

    float a0 = 0.f, a1 = 0.f, a2 = 0.f, a3 = 0.f;
    #pragma unroll 4
    for (int oi = 0; oi < 256; ++oi) {
        const float4 e = *reinterpret_cast<const float4*>(epb + (size_t)oi * SRC);
        const float h  = hpt[oi];     // scalar (s_load)
        const float vv = vo[oi];      // scalar (s_load)
        const float z0 = __builtin_amdgcn_exp2f(h + e.x);
        const float z1 = __builtin_amdgcn_exp2f(h + e.y);
        const float z2 = __builtin_amdgcn_exp2f(h + e.z);
        const float z3 = __builtin_amdgcn_exp2f(h + e.w);
        a0 = fmaf(vv, __builtin_amdgcn_rcpf(z0 + 1.f), a0);
        a1 = fmaf(vv, __builtin_amdgcn_rcpf(z1 + 1.f), a1);
        a2 = fmaf(vv, __builtin_amdgcn_rcpf(z2 + 1.f), a2);
        a3 = fmaf(vv, __builtin_amdgcn_rcpf(z3 + 1.f), a3);
    }
    float4 av; av.x = a0; av.y = a1; av.z = a2; av.w = a3;
    *reinterpret_cast<float4*>(&accs[tl][oh][4 * lane]) = av;

    const float sv = v[tid] + v[tid + 256];
    __syncthreads();

    // combine + softmax: thread owns s = tid for BOTH t rows
    const int s = tid;
    const float P0 = accs[0][0][s] + accs[0][1][s];
    const float P1 = accs[1][0][s] + accs[1][1][s];
    const float sumv = block_sum(sv, red, tid);
    const float sc0 = sumv - 2.f * P0;
    const float sc1 = sumv - 2.f * P1;

    const float2 m  = block_max2(sc0, sc1, red, tid);
    const float e0 = __expf(sc0 - m.x);
    const float e1 = __expf(sc1 - m.y);
    const float2 sE = block_sum2(e0, e1, red, tid);
    const float msk = (float)mask[b * SRC + s];
    const float mq0 = (e0 / sE.x) * msk;
    const float mq1 = (e1 / sE.y) * msk;
    const float2 sM = block_sum2(mq0, mq1, red, tid);
    const float p0 = mq0 / (sM.x + 1e-12f);
    const float p1 = mq1 / (sM.y + 1e-12f);
    p_lds[0][s] = p0;
    p_lds[1][s] = p1;
    probs_out[((size_t)(b * TGT + t0 + 0)) * SRC + s] = p0;
    probs_out[((size_t)(b * TGT + t0 + 1)) * SRC + s] = p1;
    __syncthreads();

    // context: thread owns output columns d = 2*tid, 2*tid+1, both t rows
    const float* __restrict__ encb = enc + (size_t)b * SRC * TSD + 2 * tid;
    float c00 = 0.f, c01 = 0.f, c10 = 0.f, c11 = 0.f;
    #pragma unroll 4
    for (int s2 = 0; s2 < SRC; ++s2) {
        const float2 ev = *reinterpret_cast<const float2*>(encb + (size_t)s2 * TSD);
        const float q0 = p_lds[0][s2];
        const float q1 = p_lds[1][s2];
        c00 = fmaf(q0, ev.x, c00); c01 = fmaf(q0, ev.y, c01);
        c10 = fmaf(q1, ev.x, c10); c11 = fmaf(q1, ev.y, c11);
    }
    float2 r0; r0.x = c00; r0.y = c01;
    float2 r1; r1.x = c10; r1.y = c11;
    *reinterpret_cast<float2*>(&ctx_out[((size_t)(b * TGT + t0 + 0)) * TSD + 2 * tid]) = r0;
    *reinterpret_cast<float2*>(&ctx_out[((size_t)(b * TGT + t0 + 1)) * TSD + 2 * tid]) = r1;
}

extern "C" void kernel_launch(void* const* d_in, const int* in_sizes, int n_in,
                              void* d_out, int out_size, void* d_ws, size_t ws_size,
                              hipStream_t stream) {
    const float* hid  = (const float*)d_in[0];   // (4,256,512)
    const float* enc  = (const float*)d_in[1];   // (4,256,512)
    const int*   mask = (const int*)  d_in[2];   // (4,256)
    const float* W    = (const float*)d_in[3];   // (512,1024)
    const float* bias = (const float*)d_in[4];   // (512,)
    const float* v    = (const float*)d_in[5];   // (512,)

    float* out   = (float*)d_out;
    float* ctx   = out;                       // 4*256*512
    float* probs = out + NB * TGT * TSD;      // 4*256*256

    float* hp  = (float*)d_ws;                // 1024*512 (K-scaled)
    float* epT = hp + NB * TGT * TSD;         // 4*512*256 (K-scaled, +bias, transposed)

    dim3 pb(16, 16);
    dim3 pg(TSD / 64, (NB * TGT) / 64, 2);
    proj_kernel<<<pg, pb, 0, stream>>>(hid, enc, W, bias, hp, epT);

    dim3 ag(TGT / 2, NB);
    attn_kernel<<<ag, 256, 0, stream>>>(hp, epT, enc, mask, v, ctx, probs);
}

// Round 6
// 89.566 us; speedup vs baseline: 1.2665x; 1.0434x over previous
//
#include <hip/hip_runtime.h>

#define TSD 512      // TS (feature dim)
#define SRC 256
#define TGT 256
#define NB  4        // batch
#define KSCALE 2.885390081777927f   // 2*log2(e): exp2(K*x) == exp(2x)

// ---------------------------------------------------------------------------
// Projection GEMM: 64x64 tiles, 16x16 threads, 4x4 micro-tile, BK=16.
// z=0: hp'[r][o]    = K * (hid . Wh)[r][o]                 (row-major [r][o])
// z=1: epT[b][o][s] = K * ((enc . We)[r][o] + bias[o])     (TRANSPOSED [o][s])
// ---------------------------------------------------------------------------
__global__ __launch_bounds__(256) void proj_kernel(
    const float* __restrict__ hid, const float* __restrict__ enc,
    const float* __restrict__ W, const float* __restrict__ bias,
    float* __restrict__ hp, float* __restrict__ epT)
{
    const int z = blockIdx.z;
    const float* __restrict__ X = z ? enc : hid;
    const int wofs = z ? TSD : 0;

    __shared__ float Xs[16][68];   // [k][m]
    __shared__ float Ws[16][68];   // [k][n]

    const int tx = threadIdx.x, ty = threadIdx.y;
    const int tid = ty * 16 + tx;
    const int o0 = blockIdx.x * 64;
    const int r0 = blockIdx.y * 64;

    const int m  = tid >> 2;        // 0..63
    const int kq = (tid & 3) * 4;   // 0,4,8,12

    float acc[4][4] = {};

    for (int k0 = 0; k0 < TSD; k0 += 16) {
        __syncthreads();
        float4 av = *reinterpret_cast<const float4*>(&X[(r0 + m) * TSD + k0 + kq]);
        float4 wv = *reinterpret_cast<const float4*>(&W[(o0 + m) * (2 * TSD) + wofs + k0 + kq]);
        Xs[kq + 0][m] = av.x; Xs[kq + 1][m] = av.y; Xs[kq + 2][m] = av.z; Xs[kq + 3][m] = av.w;
        Ws[kq + 0][m] = wv.x; Ws[kq + 1][m] = wv.y; Ws[kq + 2][m] = wv.z; Ws[kq + 3][m] = wv.w;
        __syncthreads();
        #pragma unroll
        for (int k = 0; k < 16; ++k) {
            float4 a  = *reinterpret_cast<const float4*>(&Xs[k][ty * 4]);
            float4 bb = *reinterpret_cast<const float4*>(&Ws[k][tx * 4]);
            float ar[4] = {a.x, a.y, a.z, a.w};
            float br[4] = {bb.x, bb.y, bb.z, bb.w};
            #pragma unroll
            for (int i = 0; i < 4; ++i)
                #pragma unroll
                for (int j = 0; j < 4; ++j)
                    acc[i][j] = fmaf(ar[i], br[j], acc[i][j]);
        }
    }

    if (z) {
        const int bb_ = r0 >> 8;              // batch of this row-tile
        const int sl  = (r0 & 255) + ty * 4;  // s within batch
        #pragma unroll
        for (int j = 0; j < 4; ++j) {
            const int o = o0 + tx * 4 + j;
            const float bj = bias[o];
            float4 val;
            val.x = (acc[0][j] + bj) * KSCALE;
            val.y = (acc[1][j] + bj) * KSCALE;
            val.z = (acc[2][j] + bj) * KSCALE;
            val.w = (acc[3][j] + bj) * KSCALE;
            *reinterpret_cast<float4*>(&epT[((size_t)bb_ * TSD + o) * SRC + sl]) = val;
        }
    } else {
        #pragma unroll
        for (int i = 0; i < 4; ++i) {
            const int r = r0 + ty * 4 + i;
            float4 o4;
            o4.x = acc[i][0] * KSCALE; o4.y = acc[i][1] * KSCALE;
            o4.z = acc[i][2] * KSCALE; o4.w = acc[i][3] * KSCALE;
            *reinterpret_cast<float4*>(&hp[r * TSD + o0 + tx * 4]) = o4;
        }
    }
}

// ---------------------------------------------------------------------------
// Reductions: 512-thr block; grp_* reduce over the 256-thread group g=tid>>8.
// ---------------------------------------------------------------------------
__device__ __forceinline__ float wave_red_sum(float v) {
    #pragma unroll
    for (int off = 1; off < 64; off <<= 1) v += __shfl_xor(v, off, 64);
    return v;
}
__device__ __forceinline__ float wave_red_max(float v) {
    #pragma unroll
    for (int off = 1; off < 64; off <<= 1) v = fmaxf(v, __shfl_xor(v, off, 64));
    return v;
}
__device__ __forceinline__ float grp_sum(float val, float (*red)[4], int g, int tid) {
    float w = wave_red_sum(val);
    __syncthreads();
    if ((tid & 63) == 0) red[g][(tid >> 6) & 3] = w;
    __syncthreads();
    return red[g][0] + red[g][1] + red[g][2] + red[g][3];
}
__device__ __forceinline__ float grp_max(float val, float (*red)[4], int g, int tid) {
    float w = wave_red_max(val);
    __syncthreads();
    if ((tid & 63) == 0) red[g][(tid >> 6) & 3] = w;
    __syncthreads();
    return fmaxf(fmaxf(red[g][0], red[g][1]), fmaxf(red[g][2], red[g][3]));
}

// ---------------------------------------------------------------------------
// Fused score + softmax + context.
// Block = 512 threads = 8 waves. Wave w owns o-slice [64w, 64w+64).
// Lane owns 4 consecutive s; each thread accumulates BOTH t-rows from one
// e-load (8 sigmoid evals / float4). h and v live in LDS as interleaved
// float2 {K*h, v} -> wave-uniform ds_read_b64 broadcasts, NO per-iter s_loads.
// score[t][s] = sumv - 2 * sum_o v[o] / (exp2(hp'[t][o] + epT'[o][s]) + 1)
// ---------------------------------------------------------------------------
__global__ __launch_bounds__(512, 4) void attn_kernel(
    const float* __restrict__ hp, const float* __restrict__ epT,
    const float* __restrict__ enc, const int* __restrict__ mask,
    const float* __restrict__ v,
    float* __restrict__ ctx_out, float* __restrict__ probs_out)
{
    __shared__ float2 hv[2][TSD];       // {K*h[t][o], v[o]}  (8 KB)
    __shared__ float accs[2][8][SRC];   // partial sums [t][wave][s] (16 KB)
    __shared__ float p_lds[2][SRC];
    __shared__ float redv[8];
    __shared__ float red2[2][4];

    const int tid = threadIdx.x;
    const int b  = blockIdx.y;
    const int t0 = blockIdx.x * 2;

    // ---- stage {h,v} interleaved into LDS; start sum(v) ----
    {
        const int tt = tid >> 8;            // 0..1
        const int o2 = (tid & 255) * 2;     // even o
        const float2 h2 = *reinterpret_cast<const float2*>(
            &hp[((size_t)(b * TGT + t0 + tt)) * TSD + o2]);
        const float2 v2 = *reinterpret_cast<const float2*>(&v[o2]);
        float4 pk; pk.x = h2.x; pk.y = v2.x; pk.z = h2.y; pk.w = v2.y;
        *reinterpret_cast<float4*>(&hv[tt][o2]) = pk;
    }
    {
        float wsum = wave_red_sum(v[tid]);
        if ((tid & 63) == 0) redv[tid >> 6] = wsum;
    }
    __syncthreads();
    float sumv = 0.f;
    #pragma unroll
    for (int i = 0; i < 8; ++i) sumv += redv[i];

    // ---- score partials ----
    const int w    = __builtin_amdgcn_readfirstlane(tid >> 6);  // wave id 0..7
    const int lane = tid & 63;
    const float* __restrict__ epb = epT + (size_t)b * TSD * SRC + 4 * lane;

    float a00 = 0.f, a01 = 0.f, a02 = 0.f, a03 = 0.f;
    float a10 = 0.f, a11 = 0.f, a12 = 0.f, a13 = 0.f;
    const int obase = w * 64;
    #pragma unroll 2
    for (int oi = 0; oi < 64; ++oi) {
        const int o = obase + oi;
        const float4 e  = *reinterpret_cast<const float4*>(epb + (size_t)o * SRC);
        const float2 h0 = hv[0][o];   // uniform addr -> broadcast ds_read_b64
        const float2 h1 = hv[1][o];
        float z;
        z = __builtin_amdgcn_exp2f(h0.x + e.x); a00 = fmaf(h0.y, __builtin_amdgcn_rcpf(z + 1.f), a00);
        z = __builtin_amdgcn_exp2f(h0.x + e.y); a01 = fmaf(h0.y, __builtin_amdgcn_rcpf(z + 1.f), a01);
        z = __builtin_amdgcn_exp2f(h0.x + e.z); a02 = fmaf(h0.y, __builtin_amdgcn_rcpf(z + 1.f), a02);
        z = __builtin_amdgcn_exp2f(h0.x + e.w); a03 = fmaf(h0.y, __builtin_amdgcn_rcpf(z + 1.f), a03);
        z = __builtin_amdgcn_exp2f(h1.x + e.x); a10 = fmaf(h1.y, __builtin_amdgcn_rcpf(z + 1.f), a10);
        z = __builtin_amdgcn_exp2f(h1.x + e.y); a11 = fmaf(h1.y, __builtin_amdgcn_rcpf(z + 1.f), a11);
        z = __builtin_amdgcn_exp2f(h1.x + e.z); a12 = fmaf(h1.y, __builtin_amdgcn_rcpf(z + 1.f), a12);
        z = __builtin_amdgcn_exp2f(h1.x + e.w); a13 = fmaf(h1.y, __builtin_amdgcn_rcpf(z + 1.f), a13);
    }
    {
        float4 r0; r0.x = a00; r0.y = a01; r0.z = a02; r0.w = a03;
        float4 r1; r1.x = a10; r1.y = a11; r1.z = a12; r1.w = a13;
        *reinterpret_cast<float4*>(&accs[0][w][4 * lane]) = r0;
        *reinterpret_cast<float4*>(&accs[1][w][4 * lane]) = r1;
    }
    __syncthreads();

    // ---- combine + softmax: group g handles target row t0+g, s = tid&255 ----
    const int g = __builtin_amdgcn_readfirstlane(tid >> 8);
    const int s = tid & 255;
    float P = 0.f;
    #pragma unroll
    for (int k = 0; k < 8; ++k) P += accs[g][k][s];
    const float score = sumv - 2.f * P;

    const float bmax = grp_max(score, red2, g, tid);
    const float eE = __expf(score - bmax);
    const float sE = grp_sum(eE, red2, g, tid);
    const float mq = (eE / sE) * (float)mask[b * SRC + s];
    const float smq = grp_sum(mq, red2, g, tid);
    const float p = mq / (smq + 1e-12f);
    p_lds[g][s] = p;
    probs_out[((size_t)(b * TGT + t0 + g)) * SRC + s] = p;
    __syncthreads();

    // ---- context: thread owns column d = tid, both t rows ----
    const float* __restrict__ encb = enc + (size_t)b * SRC * TSD + tid;
    float c0 = 0.f, c1 = 0.f;
    #pragma unroll 4
    for (int s2 = 0; s2 < SRC; ++s2) {
        const float ev = encb[(size_t)s2 * TSD];
        c0 = fmaf(p_lds[0][s2], ev, c0);
        c1 = fmaf(p_lds[1][s2], ev, c1);
    }
    ctx_out[((size_t)(b * TGT + t0 + 0)) * TSD + tid] = c0;
    ctx_out[((size_t)(b * TGT + t0 + 1)) * TSD + tid] = c1;
}

extern "C" void kernel_launch(void* const* d_in, const int* in_sizes, int n_in,
                              void* d_out, int out_size, void* d_ws, size_t ws_size,
                              hipStream_t stream) {
    const float* hid  = (const float*)d_in[0];   // (4,256,512)
    const float* enc  = (const float*)d_in[1];   // (4,256,512)
    const int*   mask = (const int*)  d_in[2];   // (4,256)
    const float* W    = (const float*)d_in[3];   // (512,1024)
    const float* bias = (const float*)d_in[4];   // (512,)
    const float* v    = (const float*)d_in[5];   // (512,)

    float* out   = (float*)d_out;
    float* ctx   = out;                       // 4*256*512
    float* probs = out + NB * TGT * TSD;      // 4*256*256

    float* hp  = (float*)d_ws;                // 1024*512 (K-scaled)
    float* epT = hp + NB * TGT * TSD;         // 4*512*256 (K-scaled, +bias, transposed)

    dim3 pb(16, 16);
    dim3 pg(TSD / 64, (NB * TGT) / 64, 2);
    proj_kernel<<<pg, pb, 0, stream>>>(hid, enc, W, bias, hp, epT);

    dim3 ag(TGT / 2, NB);
    attn_kernel<<<ag, 512, 0, stream>>>(hp, epT, enc, mask, v, ctx, probs);
}

// Round 7
// 75.318 us; speedup vs baseline: 1.5060x; 1.1892x over previous
//
#include <hip/hip_runtime.h>

#define TSD 512      // TS (feature dim)
#define SRC 256
#define TGT 256
#define NB  4        // batch
#define KSCALE 2.885390081777927f   // 2*log2(e): exp2(K*x) == exp(2x)
#define ZMAX 32768.0f               // clamp for exp product (tanh err <= 6.1e-5)

// ---------------------------------------------------------------------------
// Projection GEMM: 64x64 tiles, 16x16 threads, 4x4 micro-tile, BK=16.
// z=0: hpE[r][o]    = exp2(K * (hid . Wh)[r][o])               (row-major)
// z=1: epE[b][o][s] = exp2(K * ((enc . We)[r][o] + bias[o]))   (TRANSPOSED,
//       via LDS tile so the global store is s-coalesced)
// ---------------------------------------------------------------------------
__global__ __launch_bounds__(256) void proj_kernel(
    const float* __restrict__ hid, const float* __restrict__ enc,
    const float* __restrict__ W, const float* __restrict__ bias,
    float* __restrict__ hpE, float* __restrict__ epE)
{
    const int z = blockIdx.z;
    const float* __restrict__ X = z ? enc : hid;
    const int wofs = z ? TSD : 0;

    __shared__ float Xs[16][68];   // [k][m]
    __shared__ float Ws[16][68];   // [k][n]
    __shared__ float tile[64][68]; // [s_local][o_local] transpose staging (z=1)

    const int tx = threadIdx.x, ty = threadIdx.y;
    const int tid = ty * 16 + tx;
    const int o0 = blockIdx.x * 64;
    const int r0 = blockIdx.y * 64;

    const int m  = tid >> 2;        // 0..63
    const int kq = (tid & 3) * 4;   // 0,4,8,12

    float acc[4][4] = {};

    for (int k0 = 0; k0 < TSD; k0 += 16) {
        __syncthreads();
        float4 av = *reinterpret_cast<const float4*>(&X[(r0 + m) * TSD + k0 + kq]);
        float4 wv = *reinterpret_cast<const float4*>(&W[(o0 + m) * (2 * TSD) + wofs + k0 + kq]);
        Xs[kq + 0][m] = av.x; Xs[kq + 1][m] = av.y; Xs[kq + 2][m] = av.z; Xs[kq + 3][m] = av.w;
        Ws[kq + 0][m] = wv.x; Ws[kq + 1][m] = wv.y; Ws[kq + 2][m] = wv.z; Ws[kq + 3][m] = wv.w;
        __syncthreads();
        #pragma unroll
        for (int k = 0; k < 16; ++k) {
            float4 a  = *reinterpret_cast<const float4*>(&Xs[k][ty * 4]);
            float4 bb = *reinterpret_cast<const float4*>(&Ws[k][tx * 4]);
            float ar[4] = {a.x, a.y, a.z, a.w};
            float br[4] = {bb.x, bb.y, bb.z, bb.w};
            #pragma unroll
            for (int i = 0; i < 4; ++i)
                #pragma unroll
                for (int j = 0; j < 4; ++j)
                    acc[i][j] = fmaf(ar[i], br[j], acc[i][j]);
        }
    }

    if (z) {
        // exp2(K*(acc+bias)) -> LDS tile [s][o] -> coalesced transposed store
        const float b0 = bias[o0 + tx * 4 + 0];
        const float b1 = bias[o0 + tx * 4 + 1];
        const float b2 = bias[o0 + tx * 4 + 2];
        const float b3 = bias[o0 + tx * 4 + 3];
        __syncthreads();
        #pragma unroll
        for (int i = 0; i < 4; ++i) {
            float4 val;
            val.x = __builtin_amdgcn_exp2f((acc[i][0] + b0) * KSCALE);
            val.y = __builtin_amdgcn_exp2f((acc[i][1] + b1) * KSCALE);
            val.z = __builtin_amdgcn_exp2f((acc[i][2] + b2) * KSCALE);
            val.w = __builtin_amdgcn_exp2f((acc[i][3] + b3) * KSCALE);
            *reinterpret_cast<float4*>(&tile[ty * 4 + i][tx * 4]) = val;
        }
        __syncthreads();
        const int bb_ = r0 >> 8;              // batch of this row-tile
        const int s0  = (r0 & 255) + (tid & 15) * 4;
        #pragma unroll
        for (int it = 0; it < 4; ++it) {
            const int ol = it * 16 + (tid >> 4);
            float4 val;
            val.x = tile[(tid & 15) * 4 + 0][ol];
            val.y = tile[(tid & 15) * 4 + 1][ol];
            val.z = tile[(tid & 15) * 4 + 2][ol];
            val.w = tile[(tid & 15) * 4 + 3][ol];
            *reinterpret_cast<float4*>(&epE[((size_t)bb_ * TSD + o0 + ol) * SRC + s0]) = val;
        }
    } else {
        #pragma unroll
        for (int i = 0; i < 4; ++i) {
            const int r = r0 + ty * 4 + i;
            float4 o4;
            o4.x = __builtin_amdgcn_exp2f(acc[i][0] * KSCALE);
            o4.y = __builtin_amdgcn_exp2f(acc[i][1] * KSCALE);
            o4.z = __builtin_amdgcn_exp2f(acc[i][2] * KSCALE);
            o4.w = __builtin_amdgcn_exp2f(acc[i][3] * KSCALE);
            *reinterpret_cast<float4*>(&hpE[r * TSD + o0 + tx * 4]) = o4;
        }
    }
}

// ---------------------------------------------------------------------------
// Reductions: 512-thr block, two 256-thread groups (g = tid>>8), each group
// reduces TWO channels at once. All 512 threads must call.
// ---------------------------------------------------------------------------
__device__ __forceinline__ float wave_red_sum(float v) {
    #pragma unroll
    for (int off = 1; off < 64; off <<= 1) v += __shfl_xor(v, off, 64);
    return v;
}
__device__ __forceinline__ float wave_red_max(float v) {
    #pragma unroll
    for (int off = 1; off < 64; off <<= 1) v = fmaxf(v, __shfl_xor(v, off, 64));
    return v;
}
__device__ __forceinline__ float2 grp_sum2(float a, float b, float (*red)[2][4], int g, int tid) {
    float wa = wave_red_sum(a), wb = wave_red_sum(b);
    __syncthreads();
    if ((tid & 63) == 0) { red[g][0][(tid >> 6) & 3] = wa; red[g][1][(tid >> 6) & 3] = wb; }
    __syncthreads();
    float2 r;
    r.x = red[g][0][0] + red[g][0][1] + red[g][0][2] + red[g][0][3];
    r.y = red[g][1][0] + red[g][1][1] + red[g][1][2] + red[g][1][3];
    return r;
}
__device__ __forceinline__ float2 grp_max2(float a, float b, float (*red)[2][4], int g, int tid) {
    float wa = wave_red_max(a), wb = wave_red_max(b);
    __syncthreads();
    if ((tid & 63) == 0) { red[g][0][(tid >> 6) & 3] = wa; red[g][1][(tid >> 6) & 3] = wb; }
    __syncthreads();
    float2 r;
    r.x = fmaxf(fmaxf(red[g][0][0], red[g][0][1]), fmaxf(red[g][0][2], red[g][0][3]));
    r.y = fmaxf(fmaxf(red[g][1][0], red[g][1][1]), fmaxf(red[g][1][2], red[g][1][3]));
    return r;
}

// ---------------------------------------------------------------------------
// Fused score + softmax + context. TB=4 target rows per block.
// Block = 512 threads = 8 waves; wave w owns o-slice [64w,64w+64);
// lane owns 4 consecutive s (float4 Ee loads); each thread does 4 t-rows.
// z[t][s] = Eh[t][o] * Ee[o][s]  (== exp(2x));  term = v / (min(z,ZMAX)+1)
// 4 divisions share ONE v_rcp via reciprocal-product trick.
// score[t][s] = sumv - 2 * sum_o term
// ---------------------------------------------------------------------------
__global__ __launch_bounds__(512) void attn_kernel(
    const float* __restrict__ hpE, const float* __restrict__ epE,
    const float* __restrict__ enc, const int* __restrict__ mask,
    const float* __restrict__ v,
    float* __restrict__ ctx_out, float* __restrict__ probs_out)
{
    __shared__ float4 hv[TSD];          // {Eh[t0..t0+3][o]}   (8 KB)
    __shared__ float v_lds[TSD];        // v[o]                (2 KB)
    __shared__ float accs[4][8][SRC];   // partials [t][wave][s] (32 KB)
    __shared__ float p_lds[4][SRC];     // probs (4 KB)
    __shared__ float redv[8];
    __shared__ float red2[2][2][4];

    const int tid = threadIdx.x;
    const int b  = blockIdx.y;
    const int t0 = blockIdx.x * 4;

    // ---- stage Eh rows (packed float4 over t) + v; start sum(v) ----
    {
        const size_t base = ((size_t)(b * TGT + t0)) * TSD + tid;
        float4 pk;
        pk.x = hpE[base];
        pk.y = hpE[base + TSD];
        pk.z = hpE[base + 2 * TSD];
        pk.w = hpE[base + 3 * TSD];
        hv[tid] = pk;
        v_lds[tid] = v[tid];
    }
    {
        float wsum = wave_red_sum(v[tid]);
        if ((tid & 63) == 0) redv[tid >> 6] = wsum;
    }
    __syncthreads();
    float sumv = 0.f;
    #pragma unroll
    for (int i = 0; i < 8; ++i) sumv += redv[i];

    // ---- score partials ----
    const int w    = __builtin_amdgcn_readfirstlane(tid >> 6);  // wave id 0..7
    const int lane = tid & 63;
    const float* __restrict__ epb = epE + (size_t)b * TSD * SRC + 4 * lane;

    float acc[4][4] = {};   // [t][s-sub]
    const int obase = w * 64;
    #pragma unroll 2
    for (int oi = 0; oi < 64; ++oi) {
        const int o = obase + oi;
        const float4 ee = *reinterpret_cast<const float4*>(epb + (size_t)o * SRC);
        const float4 eh = hv[o];        // uniform -> ds_read_b128 broadcast
        const float  vv = v_lds[o];     // uniform -> ds_read_b32 broadcast
        const float ehr[4] = {eh.x, eh.y, eh.z, eh.w};
        const float eer[4] = {ee.x, ee.y, ee.z, ee.w};
        #pragma unroll
        for (int k = 0; k < 4; ++k) {
            // z' for the 4 t-rows at this s
            float z0 = fminf(ehr[0] * eer[k], ZMAX) + 1.f;
            float z1 = fminf(ehr[1] * eer[k], ZMAX) + 1.f;
            float z2 = fminf(ehr[2] * eer[k], ZMAX) + 1.f;
            float z3 = fminf(ehr[3] * eer[k], ZMAX) + 1.f;
            const float p01 = z0 * z1;
            const float p23 = z2 * z3;
            const float r   = __builtin_amdgcn_rcpf(p01 * p23);
            const float rp01 = r * p01;       // = 1/p23
            const float rp23 = r * p23;       // = 1/p01
            acc[0][k] = fmaf(vv, z1 * rp23, acc[0][k]);
            acc[1][k] = fmaf(vv, z0 * rp23, acc[1][k]);
            acc[2][k] = fmaf(vv, z3 * rp01, acc[2][k]);
            acc[3][k] = fmaf(vv, z2 * rp01, acc[3][k]);
        }
    }
    #pragma unroll
    for (int t = 0; t < 4; ++t) {
        float4 r4; r4.x = acc[t][0]; r4.y = acc[t][1]; r4.z = acc[t][2]; r4.w = acc[t][3];
        *reinterpret_cast<float4*>(&accs[t][w][4 * lane]) = r4;
    }
    __syncthreads();

    // ---- combine + softmax: group g (256 thr) handles rows {2g, 2g+1} ----
    const int g = __builtin_amdgcn_readfirstlane(tid >> 8);
    const int s = tid & 255;
    const int ta = 2 * g, tb = 2 * g + 1;
    float Pa = 0.f, Pb = 0.f;
    #pragma unroll
    for (int k = 0; k < 8; ++k) { Pa += accs[ta][k][s]; Pb += accs[tb][k][s]; }
    const float sca = sumv - 2.f * Pa;
    const float scb = sumv - 2.f * Pb;

    const float2 mx = grp_max2(sca, scb, red2, g, tid);
    const float ea = __expf(sca - mx.x);
    const float eb = __expf(scb - mx.y);
    const float2 sE = grp_sum2(ea, eb, red2, g, tid);
    const float msk = (float)mask[b * SRC + s];
    const float mqa = (ea / sE.x) * msk;
    const float mqb = (eb / sE.y) * msk;
    const float2 sM = grp_sum2(mqa, mqb, red2, g, tid);
    const float pa = mqa / (sM.x + 1e-12f);
    const float pb = mqb / (sM.y + 1e-12f);
    p_lds[ta][s] = pa;
    p_lds[tb][s] = pb;
    probs_out[((size_t)(b * TGT + t0 + ta)) * SRC + s] = pa;
    probs_out[((size_t)(b * TGT + t0 + tb)) * SRC + s] = pb;
    __syncthreads();

    // ---- context: thread owns column d = tid, all 4 t rows ----
    const float* __restrict__ encb = enc + (size_t)b * SRC * TSD + tid;
    float c0 = 0.f, c1 = 0.f, c2 = 0.f, c3 = 0.f;
    #pragma unroll 4
    for (int s2 = 0; s2 < SRC; ++s2) {
        const float ev = encb[(size_t)s2 * TSD];
        c0 = fmaf(p_lds[0][s2], ev, c0);
        c1 = fmaf(p_lds[1][s2], ev, c1);
        c2 = fmaf(p_lds[2][s2], ev, c2);
        c3 = fmaf(p_lds[3][s2], ev, c3);
    }
    ctx_out[((size_t)(b * TGT + t0 + 0)) * TSD + tid] = c0;
    ctx_out[((size_t)(b * TGT + t0 + 1)) * TSD + tid] = c1;
    ctx_out[((size_t)(b * TGT + t0 + 2)) * TSD + tid] = c2;
    ctx_out[((size_t)(b * TGT + t0 + 3)) * TSD + tid] = c3;
}

extern "C" void kernel_launch(void* const* d_in, const int* in_sizes, int n_in,
                              void* d_out, int out_size, void* d_ws, size_t ws_size,
                              hipStream_t stream) {
    const float* hid  = (const float*)d_in[0];   // (4,256,512)
    const float* enc  = (const float*)d_in[1];   // (4,256,512)
    const int*   mask = (const int*)  d_in[2];   // (4,256)
    const float* W    = (const float*)d_in[3];   // (512,1024)
    const float* bias = (const float*)d_in[4];   // (512,)
    const float* v    = (const float*)d_in[5];   // (512,)

    float* out   = (float*)d_out;
    float* ctx   = out;                       // 4*256*512
    float* probs = out + NB * TGT * TSD;      // 4*256*256

    float* hpE = (float*)d_ws;                // 1024*512: exp2(K*h)
    float* epE = hpE + NB * TGT * TSD;        // 4*512*256: exp2(K*(e+b)), transposed

    dim3 pb(16, 16);
    dim3 pg(TSD / 64, (NB * TGT) / 64, 2);
    proj_kernel<<<pg, pb, 0, stream>>>(hid, enc, W, bias, hpE, epE);

    dim3 ag(TGT / 4, NB);
    attn_kernel<<<ag, 512, 0, stream>>>(hpE, epE, enc, mask, v, ctx, probs);
}